// Round 12
// baseline (8121.400 us; speedup 1.0000x reference)
//
#include <hip/hip_runtime.h>
#include <hip/hip_bf16.h>
#include <math.h>

#define N_NODES 4096
#define WPN 32
#define HID 1024
#define VOCAB 30000
#define NCLASS 4
#define NLEAVES 1024

typedef unsigned int u32;
typedef unsigned short u16;

__device__ __forceinline__ float sigmf(float x){ return 1.f/(1.f+expf(-x)); }

// ---------------------------------------------------------------------------
// Level schedule: depth[i] via iterative relaxation in LDS, then counting sort.
// Also zeroes node_h row 0 (root parent).
// ---------------------------------------------------------------------------
__global__ __launch_bounds__(1024) void k_levels(const int* __restrict__ parent,
                                                 int* __restrict__ meta,
                                                 int* __restrict__ lstart,
                                                 int* __restrict__ order,
                                                 float* __restrict__ node_h){
  __shared__ int dep[N_NODES];
  __shared__ int dpt[N_NODES];
  __shared__ int cnt[N_NODES];
  __shared__ int changed, maxd;
  const int t = threadIdx.x;
  for(int i=t;i<N_NODES;i+=1024){ dep[i]=parent[i]-1; dpt[i]=0; cnt[i]=0; }
  if(t==0){ maxd=0; }
  node_h[t]=0.f;  // 1024 threads == HID: zero root-parent row
  __syncthreads();
  while(true){
    if(t==0) changed=0;
    __syncthreads();
    bool ch=false;
    for(int i=t;i<N_NODES;i+=1024){
      int d = (dep[i]<0)? 0 : (dpt[dep[i]]+1);
      if(d>dpt[i]){ dpt[i]=d; ch=true; }
    }
    if(ch) changed=1;
    __syncthreads();
    if(!changed) break;
    __syncthreads();
  }
  __syncthreads();
  for(int i=t;i<N_NODES;i+=1024){ atomicAdd(&cnt[dpt[i]],1); atomicMax(&maxd,dpt[i]); }
  __syncthreads();
  // inclusive scan of cnt -> sc (reuse dep)
  int* sc = dep;
  for(int i=t;i<N_NODES;i+=1024) sc[i]=cnt[i];
  __syncthreads();
  for(int off=1; off<N_NODES; off<<=1){
    int v[4];
    #pragma unroll
    for(int u=0;u<4;u++){ int i=t+u*1024; v[u] = (i>=off)? sc[i-off] : 0; }
    __syncthreads();
    #pragma unroll
    for(int u=0;u<4;u++){ int i=t+u*1024; sc[i]+=v[u]; }
    __syncthreads();
  }
  for(int i=t;i<N_NODES;i+=1024) lstart[i+1]=sc[i];
  if(t==0){ lstart[0]=0; meta[0]=maxd+1; }
  // exclusive starts into cnt for scatter
  for(int i=t;i<N_NODES;i+=1024) cnt[i]=sc[i]-cnt[i];
  __syncthreads();
  for(int i=t;i<N_NODES;i+=1024){
    int pos = atomicAdd(&cnt[dpt[i]],1);
    order[pos]=i;
  }
}

// ---------------------------------------------------------------------------
// E [HID][VOCAB] f32  ->  ET [VOCAB][HID] f32  (tiled transpose)
// ---------------------------------------------------------------------------
__global__ __launch_bounds__(256) void k_transpose(const float* __restrict__ E,
                                                   float* __restrict__ ET){
  __shared__ float tile[32][33];
  const int v0 = blockIdx.x*32, h0 = blockIdx.y*32;
  const int tx = threadIdx.x%32, ty = threadIdx.x/32;   // ty 0..7
  #pragma unroll
  for(int i=0;i<4;i++){
    int h = h0+ty+8*i, v = v0+tx;
    tile[ty+8*i][tx] = (v<VOCAB)? E[(size_t)h*VOCAB + v] : 0.f;
  }
  __syncthreads();
  #pragma unroll
  for(int i=0;i<4;i++){
    int v = v0+ty+8*i, h = h0+tx;
    if(v<VOCAB) ET[(size_t)v*HID + h] = tile[tx][ty+8*i];
  }
}

// ---------------------------------------------------------------------------
// xe[n,h] = sum_l w[n,l] * ET[idx[n,l], h]   (one block per node, coalesced)
// ---------------------------------------------------------------------------
__global__ __launch_bounds__(256) void k_xe(const float* __restrict__ ET,
                                            const float* __restrict__ xw,
                                            const int* __restrict__ xi,
                                            float* __restrict__ xe){
  const int n = blockIdx.x;
  __shared__ float w[WPN]; __shared__ int id[WPN];
  const int t = threadIdx.x;
  if(t<WPN){ w[t]=xw[n*WPN+t]; id[t]=xi[n*WPN+t]; }
  __syncthreads();
  const int h0 = t*4;
  float a0=0,a1=0,a2=0,a3=0;
  for(int l=0;l<WPN;l++){
    const float4 e = *(const float4*)(ET + (size_t)id[l]*HID + h0);
    const float wl = w[l];
    a0 += wl*e.x; a1 += wl*e.y; a2 += wl*e.z; a3 += wl*e.w;
  }
  *(float4*)(xe + (size_t)n*HID + h0) = make_float4(a0,a1,a2,a3);
}

// Fallback when ws too small for fp32 ET: direct strided gather from E.
__global__ __launch_bounds__(256) void k_xe_noET(const float* __restrict__ E,
                                                 const float* __restrict__ xw,
                                                 const int* __restrict__ xi,
                                                 float* __restrict__ xe){
  const int n = blockIdx.x;
  __shared__ float w[WPN]; __shared__ int id[WPN];
  const int t = threadIdx.x;
  if(t<WPN){ w[t]=xw[n*WPN+t]; id[t]=xi[n*WPN+t]; }
  __syncthreads();
  const int h0 = t*4;
  float acc[4]={0,0,0,0};
  for(int l=0;l<WPN;l++){
    const float wl=w[l]; const int ix=id[l];
    #pragma unroll
    for(int j=0;j<4;j++) acc[j] += wl*E[(size_t)(h0+j)*VOCAB + ix];
  }
  *(float4*)(xe + (size_t)n*HID + h0) = make_float4(acc[0],acc[1],acc[2],acc[3]);
}

// ---------------------------------------------------------------------------
// Input-side projections: out_g[n,o] = b_g[o] + sum_k xe[n,k]*W_g[o,k]
// 64x64 tile, BK=32, k-major LDS, 4x4 micro-tile.
// ---------------------------------------------------------------------------
__global__ __launch_bounds__(256) void k_gemm_in(const float* __restrict__ xe,
  const float* __restrict__ W0,const float* __restrict__ W1,const float* __restrict__ W2,
  const float* __restrict__ b0,const float* __restrict__ b1,const float* __restrict__ b2,
  float* __restrict__ o0p,float* __restrict__ o1p,float* __restrict__ o2p){
  __shared__ float A[32*68];
  __shared__ float B[32*68];
  const int g=blockIdx.z;
  const float* W  = (g==0)?W0:((g==1)?W1:W2);
  const float* bi = (g==0)?b0:((g==1)?b1:b2);
  float* out      = (g==0)?o0p:((g==1)?o1p:o2p);
  const int n0=blockIdx.x<<6, q0=blockIdx.y<<6;
  const int t=threadIdx.x, tx=t&15, ty=t>>4;
  float acc[4][4]={};
  for(int k0=0;k0<HID;k0+=32){
    #pragma unroll
    for(int m=0;m<2;m++){
      int idx=t+(m<<8); int r=idx>>3; int c4=(idx&7)<<2;
      float4 v=*(const float4*)(xe+(size_t)(n0+r)*HID+k0+c4);
      A[(c4+0)*68+r]=v.x; A[(c4+1)*68+r]=v.y; A[(c4+2)*68+r]=v.z; A[(c4+3)*68+r]=v.w;
      float4 u=*(const float4*)(W+(size_t)(q0+r)*HID+k0+c4);
      B[(c4+0)*68+r]=u.x; B[(c4+1)*68+r]=u.y; B[(c4+2)*68+r]=u.z; B[(c4+3)*68+r]=u.w;
    }
    __syncthreads();
    #pragma unroll 8
    for(int k=0;k<32;k++){
      const float4 a=*(const float4*)&A[k*68+(ty<<2)];
      const float4 b=*(const float4*)&B[k*68+(tx<<2)];
      acc[0][0]+=a.x*b.x; acc[0][1]+=a.x*b.y; acc[0][2]+=a.x*b.z; acc[0][3]+=a.x*b.w;
      acc[1][0]+=a.y*b.x; acc[1][1]+=a.y*b.y; acc[1][2]+=a.y*b.z; acc[1][3]+=a.y*b.w;
      acc[2][0]+=a.z*b.x; acc[2][1]+=a.z*b.y; acc[2][2]+=a.z*b.z; acc[2][3]+=a.z*b.w;
      acc[3][0]+=a.w*b.x; acc[3][1]+=a.w*b.y; acc[3][2]+=a.w*b.z; acc[3][3]+=a.w*b.w;
    }
    __syncthreads();
  }
  const float4 bb=*(const float4*)(bi+q0+(tx<<2));
  #pragma unroll
  for(int i=0;i<4;i++){
    const int n=n0+(ty<<2)+i;
    float4 r4 = make_float4(acc[i][0]+bb.x, acc[i][1]+bb.y, acc[i][2]+bb.z, acc[i][3]+bb.w);
    *(float4*)(out+(size_t)n*HID+q0+(tx<<2)) = r4;
  }
}

// ---------------------------------------------------------------------------
// Persistent level-synchronous recurrence, v10 "decoupled fan-out":
//  Round-11 lesson: broadcast traffic per node = (blocks-per-group) x 4KB x 2.
//  v9's 128-block groups quadrupled traffic (FETCH 81->483MB) and thrashed
//  the 4MB XCD-L2 -> dur 4x worse despite 2x occupancy. v10 decouples:
//   - 16 node-groups x 32 blocks (v8's broadcast cost), 512 blocks total.
//   - group g = blockIdx&15 -> a group's blocks still share one XCD
//     (b mod 8 fixed); 2 groups per XCD. Per-block serial chain HALVES.
//   - 2 blocks/CU co-resident (the v8 missing piece): launch_bounds(512,4)
//     caps VGPR at 128 (v8 measured 124 w/ this payload), Uh as bf16 in
//     64KB LDS (2x64=128<=160KB). 16 waves/CU = 2x latency hiding.
//  Residency arithmetic exact -> no round-7-style deadlock.
// ---------------------------------------------------------------------------
#define REC_GRID 512
#define GRPSH 5
#define GRP   (1<<GRPSH)            // 32 blocks per tree-group
#define NGRP  (REC_GRID>>GRPSH)     // 16 tree-groups

__device__ __forceinline__ void gbar(u32* bar){
  __syncthreads();
  if(threadIdx.x==0){
    __threadfence();
    u32* gen  = bar;
    u32* gcnt = bar + 16 + ((blockIdx.x>>GRPSH)<<4);
    u32* root = bar + 16 + (NGRP<<4);
    u32 g = __hip_atomic_load(gen, __ATOMIC_RELAXED, __HIP_MEMORY_SCOPE_AGENT);
    u32 a = __hip_atomic_fetch_add(gcnt, 1u, __ATOMIC_ACQ_REL, __HIP_MEMORY_SCOPE_AGENT);
    if(a == GRP-1u){
      __hip_atomic_store(gcnt, 0u, __ATOMIC_RELAXED, __HIP_MEMORY_SCOPE_AGENT);
      u32 b = __hip_atomic_fetch_add(root, 1u, __ATOMIC_ACQ_REL, __HIP_MEMORY_SCOPE_AGENT);
      if(b == NGRP-1u){
        __hip_atomic_store(root, 0u, __ATOMIC_RELAXED, __HIP_MEMORY_SCOPE_AGENT);
        __hip_atomic_fetch_add(gen, 1u, __ATOMIC_RELEASE, __HIP_MEMORY_SCOPE_AGENT);
      }
    }
    while(__hip_atomic_load(gen, __ATOMIC_ACQUIRE, __HIP_MEMORY_SCOPE_AGENT)==g){
      __builtin_amdgcn_s_sleep(8);
    }
    __threadfence();
  }
  __syncthreads();
}

// group-local barrier: the 32 blocks of node-group xg (same XCD).
__device__ __forceinline__ void gbar_grp(u32* bar, int xg){
  __syncthreads();
  if(threadIdx.x==0){
    __threadfence();
    u32* gcnt = bar + 512 + (xg<<4);
    u32* ggen = bar + 512 + (xg<<4) + 8;
    u32 g = __hip_atomic_load(ggen, __ATOMIC_RELAXED, __HIP_MEMORY_SCOPE_AGENT);
    u32 a = __hip_atomic_fetch_add(gcnt, 1u, __ATOMIC_ACQ_REL, __HIP_MEMORY_SCOPE_AGENT);
    if(a == 31u){
      __hip_atomic_store(gcnt, 0u, __ATOMIC_RELAXED, __HIP_MEMORY_SCOPE_AGENT);
      __hip_atomic_fetch_add(ggen, 1u, __ATOMIC_RELEASE, __HIP_MEMORY_SCOPE_AGENT);
    }else{
      while(__hip_atomic_load(ggen, __ATOMIC_ACQUIRE, __HIP_MEMORY_SCOPE_AGENT)==g){
        __builtin_amdgcn_s_sleep(4);
      }
    }
    __threadfence();
  }
  __syncthreads();
}

// combine two accumulator slots a,b across lane stride s.
__device__ __forceinline__ float comb(float a, float b, int s, int lane){
  const bool hi = (lane & s) != 0;
  float send = hi ? a : b;
  float sel  = hi ? b : a;
  return sel + __shfl_xor(send, s, 64);
}

__device__ __forceinline__ u32 packbf(float lo, float hi){
  u32 x=__float_as_uint(lo), y=__float_as_uint(hi);
  x = (x + 0x7fffu + ((x>>16)&1u)) >> 16;
  y = (y + 0x7fffu + ((y>>16)&1u)) & 0xffff0000u;
  return y | x;
}
__device__ __forceinline__ float bf_lo(u32 u){ return __uint_as_float(u<<16); }
__device__ __forceinline__ float bf_hi(u32 u){ return __uint_as_float(u & 0xffff0000u); }
__device__ __forceinline__ u16 f2bf16(float f){
  u32 x=__float_as_uint(f);
  return (u16)((x + 0x7fffu + ((x>>16)&1u))>>16);
}
__device__ __forceinline__ float bfu(u16 v){ return __uint_as_float(((u32)v)<<16); }

#define PIN1(v) asm volatile("" : "+v"(v))

__global__ __launch_bounds__(512,4) void k_rec(
    const int* __restrict__ parent,
    const float* __restrict__ Uz, const float* __restrict__ Ur, const float* __restrict__ Uh,
    float* __restrict__ wz, float* __restrict__ wr, float* __restrict__ wh,
    float* __restrict__ node_h,
    const int* __restrict__ meta, const int* __restrict__ lstart, const int* __restrict__ order,
    u32* __restrict__ bar){
  __shared__ u16 UhL[32*HID];        // 64 KB: this block's 32 rows of U_h (bf16)
  const int t=threadIdx.x, lane=t&63, wv=t>>6;   // 8 waves
  const int g = blockIdx.x & 15;     // node-group (32 blocks, one XCD)
  const int i = blockIdx.x >> 4;     // 0..31 within group
  const bool isZ = i < 16;
  const int rA  = ((i&15)<<6) + (wv<<3);  // phase A: 8 rows per wave
  const int rC0 = i<<5;                   // phase C: block's 32 rows
  const int nlev = meta[0];
  const int l4 = lane<<2;

  // ---- one-time staging ----
  // Uz/Ur rows -> bf16-packed registers (64 u32/lane), pinned.
  const float* UA = isZ ? Uz : Ur;
  u32 uap[8][8];
  #pragma unroll
  for(int r=0;r<8;r++)
    #pragma unroll
    for(int c=0;c<4;c++){
      const float4 v = *(const float4*)(UA + (size_t)(rA+r)*HID + (c<<8) + l4);
      uap[r][c*2]   = packbf(v.x, v.y);
      uap[r][c*2+1] = packbf(v.z, v.w);
      PIN1(uap[r][c*2]); PIN1(uap[r][c*2+1]);
    }
  // Uh rows -> bf16 LDS.
  for(int x=t; x<32*HID; x+=512) UhL[x] = f2bf16(Uh[(size_t)rC0*HID + x]);
  __syncthreads();

  for(int lev=0; lev<nlev; ++lev){
    const int s=lstart[lev];
    const int L=lstart[lev+1]-s;
    // ---- phase A: z (i<16) or r (i>=16) rows for this group's nodes ----
    {
      int jj = g;
      int n = (jj<L)? order[s+jj] : 0;
      int p = (jj<L)? parent[n]   : 0;
      while(jj<L){
        const int jn = jj+16;
        int n2=0, p2=0;
        if(jn<L){ n2=order[s+jn]; p2=parent[n2]; }   // next-node meta, issued early
        const float* ph = node_h + (size_t)p*HID;
        float4 bb[4];
        #pragma unroll
        for(int c=0;c<4;c++) bb[c] = *(const float4*)(ph + (c<<8) + l4);
        const int myrow = rA + (lane&7);
        float wv0 = isZ ? wz[(size_t)n*HID + myrow] : wr[(size_t)n*HID + myrow];
        float pv0 = isZ ? 0.f : node_h[(size_t)p*HID + myrow];
        float a0=0.f,a1=0.f,a2=0.f,a3=0.f,a4=0.f,a5=0.f,a6=0.f,a7=0.f;
        #pragma unroll
        for(int c=0;c<4;c++){
          const float4 b=bb[c];
          #define ROWFMA(acc,r) { const u32 p0=uap[r][c*2], p1=uap[r][c*2+1]; \
            acc=fmaf(bf_lo(p0),b.x,acc); acc=fmaf(bf_hi(p0),b.y,acc); \
            acc=fmaf(bf_lo(p1),b.z,acc); acc=fmaf(bf_hi(p1),b.w,acc); }
          ROWFMA(a0,0) ROWFMA(a1,1) ROWFMA(a2,2) ROWFMA(a3,3)
          ROWFMA(a4,4) ROWFMA(a5,5) ROWFMA(a6,6) ROWFMA(a7,7)
          #undef ROWFMA
        }
        float c0=comb(a0,a1,1,lane), c1=comb(a2,a3,1,lane);
        float c2=comb(a4,a5,1,lane), c3=comb(a6,a7,1,lane);
        float d0=comb(c0,c1,2,lane), d1=comb(c2,c3,2,lane);
        float v=comb(d0,d1,4,lane);
        v+=__shfl_xor(v,8,64); v+=__shfl_xor(v,16,64); v+=__shfl_xor(v,32,64);
        if(lane<8){
          const size_t idx=(size_t)n*HID+rA+lane;
          if(isZ) wz[idx]=sigmf(wv0+v);
          else    wr[idx]=sigmf(wv0+v)*pv0;
        }
        jj=jn; n=n2; p=p2;
      }
    }
    gbar_grp(bar, g);    // r/z producers and consumers are all in this group
    // ---- phase C: h-candidate + state update (4 rows/wave, bf16 Uh in LDS) ----
    {
      int jj = g;
      int n = (jj<L)? order[s+jj] : 0;
      int p = (jj<L)? parent[n]   : 0;
      while(jj<L){
        const int jn = jj+16;
        int n2=0, p2=0;
        if(jn<L){ n2=order[s+jn]; p2=parent[n2]; }
        const float* bw = wr + (size_t)n*HID;
        float4 bb[4];
        #pragma unroll
        for(int c=0;c<4;c++) bb[c] = *(const float4*)(bw + (c<<8) + l4);
        const int myrow = rC0 + (wv<<2) + (lane&3);
        float zv0 = wz[(size_t)n*HID + myrow];
        float wh0 = wh[(size_t)n*HID + myrow];
        float pv0 = node_h[(size_t)p*HID + myrow];
        float a0=0.f,a1=0.f,a2=0.f,a3=0.f;
        #pragma unroll
        for(int c=0;c<4;c++){
          const float4 b=bb[c];
          const ushort4 q0 = *(const ushort4*)&UhL[((wv<<2)+0)*HID + (c<<8) + l4];
          const ushort4 q1 = *(const ushort4*)&UhL[((wv<<2)+1)*HID + (c<<8) + l4];
          const ushort4 q2 = *(const ushort4*)&UhL[((wv<<2)+2)*HID + (c<<8) + l4];
          const ushort4 q3 = *(const ushort4*)&UhL[((wv<<2)+3)*HID + (c<<8) + l4];
          a0=fmaf(bfu(q0.x),b.x,a0); a0=fmaf(bfu(q0.y),b.y,a0); a0=fmaf(bfu(q0.z),b.z,a0); a0=fmaf(bfu(q0.w),b.w,a0);
          a1=fmaf(bfu(q1.x),b.x,a1); a1=fmaf(bfu(q1.y),b.y,a1); a1=fmaf(bfu(q1.z),b.z,a1); a1=fmaf(bfu(q1.w),b.w,a1);
          a2=fmaf(bfu(q2.x),b.x,a2); a2=fmaf(bfu(q2.y),b.y,a2); a2=fmaf(bfu(q2.z),b.z,a2); a2=fmaf(bfu(q2.w),b.w,a2);
          a3=fmaf(bfu(q3.x),b.x,a3); a3=fmaf(bfu(q3.y),b.y,a3); a3=fmaf(bfu(q3.z),b.z,a3); a3=fmaf(bfu(q3.w),b.w,a3);
        }
        float c0=comb(a0,a1,1,lane), c1=comb(a2,a3,1,lane);
        float v=comb(c0,c1,2,lane);
        v+=__shfl_xor(v,4,64); v+=__shfl_xor(v,8,64);
        v+=__shfl_xor(v,16,64); v+=__shfl_xor(v,32,64);
        if(lane<4){
          const float c=tanhf(wh0+v);
          node_h[(size_t)(n+1)*HID+myrow]=zv0*pv0+(1.f-zv0)*c;
        }
        jj=jn; n=n2; p=p2;
      }
    }
    gbar(bar);   // level boundary: parents cross groups -> global
  }
}

// ---------------------------------------------------------------------------
// Leaf max + softmax + loss. Output: FP32 pred[4], loss.
// ---------------------------------------------------------------------------
__global__ __launch_bounds__(1024) void k_final(const float* __restrict__ node_h,
                                                const int* __restrict__ leaf,
                                                const float* __restrict__ Wout,
                                                const float* __restrict__ bout,
                                                const float* __restrict__ y,
                                                float* __restrict__ out){
  __shared__ int li[NLEAVES];
  __shared__ float fs[HID];
  __shared__ float logits[NCLASS];
  const int t=threadIdx.x;
  li[t]=leaf[t];
  __syncthreads();
  float m=-INFINITY;
  for(int l=0;l<NLEAVES;l++) m = fmaxf(m, node_h[(size_t)li[l]*HID + t]);
  fs[t]=m;
  __syncthreads();
  const int wave=t>>6, lane=t&63;
  if(wave<NCLASS){
    float p=0.f;
    for(int h=lane;h<HID;h+=64) p += Wout[wave*HID+h]*fs[h];
    for(int off=32; off; off>>=1) p += __shfl_down(p, off);
    if(lane==0) logits[wave]=p+bout[wave];
  }
  __syncthreads();
  if(t==0){
    float mx = fmaxf(fmaxf(logits[0],logits[1]),fmaxf(logits[2],logits[3]));
    float ev[NCLASS]; float es=0.f;
    #pragma unroll
    for(int c=0;c<NCLASS;c++){ ev[c]=expf(logits[c]-mx); es+=ev[c]; }
    float loss=0.f;
    #pragma unroll
    for(int c=0;c<NCLASS;c++){
      float p=ev[c]/es;
      out[c]=p;
      float d=y[c]-p; loss+=d*d;
    }
    out[NCLASS]=loss;
  }
}

// ---------------------------------------------------------------------------
extern "C" void kernel_launch(void* const* d_in, const int* in_sizes, int n_in,
                              void* d_out, int out_size, void* d_ws, size_t ws_size,
                              hipStream_t stream){
  (void)in_sizes; (void)n_in; (void)out_size;
  const float* x_word=(const float*)d_in[0];
  const int*   x_index=(const int*)d_in[1];
  const int*   parent =(const int*)d_in[2];
  const int*   leaf   =(const int*)d_in[3];
  const float* y      =(const float*)d_in[4];
  const float* E      =(const float*)d_in[5];
  const float* W_z=(const float*)d_in[6];  const float* U_z=(const float*)d_in[7];  const float* b_z=(const float*)d_in[8];
  const float* W_r=(const float*)d_in[9];  const float* U_r=(const float*)d_in[10]; const float* b_r=(const float*)d_in[11];
  const float* W_h=(const float*)d_in[12]; const float* U_h=(const float*)d_in[13]; const float* b_h=(const float*)d_in[14];
  const float* W_out=(const float*)d_in[15]; const float* b_out=(const float*)d_in[16];

  size_t off=0;
  char* wsb=(char*)d_ws;
  auto alloc=[&](size_t b)->void*{ void* p=wsb+off; off=(off+b+255)&~(size_t)255; return p; };
  u32*  bar    = (u32*)  alloc(4096);
  int*  meta   = (int*)  alloc(256);
  int*  lstart = (int*)  alloc((N_NODES+1)*sizeof(int));
  int*  order  = (int*)  alloc(N_NODES*sizeof(int));
  float* node_h= (float*)alloc((size_t)(N_NODES+1)*HID*sizeof(float));
  float* xe    = (float*)alloc((size_t)N_NODES*HID*sizeof(float));
  float* wz    = (float*)alloc((size_t)N_NODES*HID*sizeof(float));
  float* wr    = (float*)alloc((size_t)N_NODES*HID*sizeof(float));
  float* wh    = (float*)alloc((size_t)N_NODES*HID*sizeof(float));
  float* ET    = (float*)(wsb+off);
  const size_t need_ET = off + (size_t)VOCAB*HID*sizeof(float);
  const bool useET = (ws_size >= need_ET);

  hipMemsetAsync(bar, 0, 4096, stream);
  k_levels<<<1,1024,0,stream>>>(parent, meta, lstart, order, node_h);
  if(useET){
    k_transpose<<<dim3((VOCAB+31)/32, HID/32),256,0,stream>>>(E, ET);
    k_xe<<<N_NODES,256,0,stream>>>(ET, x_word, x_index, xe);
  }else{
    k_xe_noET<<<N_NODES,256,0,stream>>>(E, x_word, x_index, xe);
  }
  k_gemm_in<<<dim3(N_NODES/64, HID/64, 3),256,0,stream>>>(xe, W_z,W_r,W_h, b_z,b_r,b_h, wz,wr,wh);
  k_rec<<<REC_GRID,512,0,stream>>>(parent, U_z,U_r,U_h, wz,wr,wh, node_h, meta, lstart, order, bar);
  k_final<<<1,1024,0,stream>>>(node_h, leaf, W_out, b_out, y, (float*)d_out);
}

// Round 13
// 7011.519 us; speedup vs baseline: 1.1583x; 1.1583x over previous
//
#include <hip/hip_runtime.h>
#include <hip/hip_bf16.h>
#include <math.h>

#define N_NODES 4096
#define WPN 32
#define HID 1024
#define VOCAB 30000
#define NCLASS 4
#define NLEAVES 1024

typedef unsigned int u32;
typedef unsigned short u16;

__device__ __forceinline__ float sigmf(float x){ return 1.f/(1.f+expf(-x)); }

// ---------------------------------------------------------------------------
// Level schedule: depth[i] via iterative relaxation in LDS, then counting sort.
// Also zeroes node_h row 0 (root parent).
// ---------------------------------------------------------------------------
__global__ __launch_bounds__(1024) void k_levels(const int* __restrict__ parent,
                                                 int* __restrict__ meta,
                                                 int* __restrict__ lstart,
                                                 int* __restrict__ order,
                                                 float* __restrict__ node_h){
  __shared__ int dep[N_NODES];
  __shared__ int dpt[N_NODES];
  __shared__ int cnt[N_NODES];
  __shared__ int changed, maxd;
  const int t = threadIdx.x;
  for(int i=t;i<N_NODES;i+=1024){ dep[i]=parent[i]-1; dpt[i]=0; cnt[i]=0; }
  if(t==0){ maxd=0; }
  node_h[t]=0.f;  // 1024 threads == HID: zero root-parent row
  __syncthreads();
  while(true){
    if(t==0) changed=0;
    __syncthreads();
    bool ch=false;
    for(int i=t;i<N_NODES;i+=1024){
      int d = (dep[i]<0)? 0 : (dpt[dep[i]]+1);
      if(d>dpt[i]){ dpt[i]=d; ch=true; }
    }
    if(ch) changed=1;
    __syncthreads();
    if(!changed) break;
    __syncthreads();
  }
  __syncthreads();
  for(int i=t;i<N_NODES;i+=1024){ atomicAdd(&cnt[dpt[i]],1); atomicMax(&maxd,dpt[i]); }
  __syncthreads();
  // inclusive scan of cnt -> sc (reuse dep)
  int* sc = dep;
  for(int i=t;i<N_NODES;i+=1024) sc[i]=cnt[i];
  __syncthreads();
  for(int off=1; off<N_NODES; off<<=1){
    int v[4];
    #pragma unroll
    for(int u=0;u<4;u++){ int i=t+u*1024; v[u] = (i>=off)? sc[i-off] : 0; }
    __syncthreads();
    #pragma unroll
    for(int u=0;u<4;u++){ int i=t+u*1024; sc[i]+=v[u]; }
    __syncthreads();
  }
  for(int i=t;i<N_NODES;i+=1024) lstart[i+1]=sc[i];
  if(t==0){ lstart[0]=0; meta[0]=maxd+1; }
  // exclusive starts into cnt for scatter
  for(int i=t;i<N_NODES;i+=1024) cnt[i]=sc[i]-cnt[i];
  __syncthreads();
  for(int i=t;i<N_NODES;i+=1024){
    int pos = atomicAdd(&cnt[dpt[i]],1);
    order[pos]=i;
  }
}

// ---------------------------------------------------------------------------
// E [HID][VOCAB] f32  ->  ET [VOCAB][HID] f32  (tiled transpose)
// ---------------------------------------------------------------------------
__global__ __launch_bounds__(256) void k_transpose(const float* __restrict__ E,
                                                   float* __restrict__ ET){
  __shared__ float tile[32][33];
  const int v0 = blockIdx.x*32, h0 = blockIdx.y*32;
  const int tx = threadIdx.x%32, ty = threadIdx.x/32;   // ty 0..7
  #pragma unroll
  for(int i=0;i<4;i++){
    int h = h0+ty+8*i, v = v0+tx;
    tile[ty+8*i][tx] = (v<VOCAB)? E[(size_t)h*VOCAB + v] : 0.f;
  }
  __syncthreads();
  #pragma unroll
  for(int i=0;i<4;i++){
    int v = v0+ty+8*i, h = h0+tx;
    if(v<VOCAB) ET[(size_t)v*HID + h] = tile[tx][ty+8*i];
  }
}

// ---------------------------------------------------------------------------
// xe[n,h] = sum_l w[n,l] * ET[idx[n,l], h]   (one block per node, coalesced)
// ---------------------------------------------------------------------------
__global__ __launch_bounds__(256) void k_xe(const float* __restrict__ ET,
                                            const float* __restrict__ xw,
                                            const int* __restrict__ xi,
                                            float* __restrict__ xe){
  const int n = blockIdx.x;
  __shared__ float w[WPN]; __shared__ int id[WPN];
  const int t = threadIdx.x;
  if(t<WPN){ w[t]=xw[n*WPN+t]; id[t]=xi[n*WPN+t]; }
  __syncthreads();
  const int h0 = t*4;
  float a0=0,a1=0,a2=0,a3=0;
  for(int l=0;l<WPN;l++){
    const float4 e = *(const float4*)(ET + (size_t)id[l]*HID + h0);
    const float wl = w[l];
    a0 += wl*e.x; a1 += wl*e.y; a2 += wl*e.z; a3 += wl*e.w;
  }
  *(float4*)(xe + (size_t)n*HID + h0) = make_float4(a0,a1,a2,a3);
}

// Fallback when ws too small for fp32 ET: direct strided gather from E.
__global__ __launch_bounds__(256) void k_xe_noET(const float* __restrict__ E,
                                                 const float* __restrict__ xw,
                                                 const int* __restrict__ xi,
                                                 float* __restrict__ xe){
  const int n = blockIdx.x;
  __shared__ float w[WPN]; __shared__ int id[WPN];
  const int t = threadIdx.x;
  if(t<WPN){ w[t]=xw[n*WPN+t]; id[t]=xi[n*WPN+t]; }
  __syncthreads();
  const int h0 = t*4;
  float acc[4]={0,0,0,0};
  for(int l=0;l<WPN;l++){
    const float wl=w[l]; const int ix=id[l];
    #pragma unroll
    for(int j=0;j<4;j++) acc[j] += wl*E[(size_t)(h0+j)*VOCAB + ix];
  }
  *(float4*)(xe + (size_t)n*HID + h0) = make_float4(acc[0],acc[1],acc[2],acc[3]);
}

// ---------------------------------------------------------------------------
// Input-side projections: out_g[n,o] = b_g[o] + sum_k xe[n,k]*W_g[o,k]
// 64x64 tile, BK=32, k-major LDS, 4x4 micro-tile.
// ---------------------------------------------------------------------------
__global__ __launch_bounds__(256) void k_gemm_in(const float* __restrict__ xe,
  const float* __restrict__ W0,const float* __restrict__ W1,const float* __restrict__ W2,
  const float* __restrict__ b0,const float* __restrict__ b1,const float* __restrict__ b2,
  float* __restrict__ o0p,float* __restrict__ o1p,float* __restrict__ o2p){
  __shared__ float A[32*68];
  __shared__ float B[32*68];
  const int g=blockIdx.z;
  const float* W  = (g==0)?W0:((g==1)?W1:W2);
  const float* bi = (g==0)?b0:((g==1)?b1:b2);
  float* out      = (g==0)?o0p:((g==1)?o1p:o2p);
  const int n0=blockIdx.x<<6, q0=blockIdx.y<<6;
  const int t=threadIdx.x, tx=t&15, ty=t>>4;
  float acc[4][4]={};
  for(int k0=0;k0<HID;k0+=32){
    #pragma unroll
    for(int m=0;m<2;m++){
      int idx=t+(m<<8); int r=idx>>3; int c4=(idx&7)<<2;
      float4 v=*(const float4*)(xe+(size_t)(n0+r)*HID+k0+c4);
      A[(c4+0)*68+r]=v.x; A[(c4+1)*68+r]=v.y; A[(c4+2)*68+r]=v.z; A[(c4+3)*68+r]=v.w;
      float4 u=*(const float4*)(W+(size_t)(q0+r)*HID+k0+c4);
      B[(c4+0)*68+r]=u.x; B[(c4+1)*68+r]=u.y; B[(c4+2)*68+r]=u.z; B[(c4+3)*68+r]=u.w;
    }
    __syncthreads();
    #pragma unroll 8
    for(int k=0;k<32;k++){
      const float4 a=*(const float4*)&A[k*68+(ty<<2)];
      const float4 b=*(const float4*)&B[k*68+(tx<<2)];
      acc[0][0]+=a.x*b.x; acc[0][1]+=a.x*b.y; acc[0][2]+=a.x*b.z; acc[0][3]+=a.x*b.w;
      acc[1][0]+=a.y*b.x; acc[1][1]+=a.y*b.y; acc[1][2]+=a.y*b.z; acc[1][3]+=a.y*b.w;
      acc[2][0]+=a.z*b.x; acc[2][1]+=a.z*b.y; acc[2][2]+=a.z*b.z; acc[2][3]+=a.z*b.w;
      acc[3][0]+=a.w*b.x; acc[3][1]+=a.w*b.y; acc[3][2]+=a.w*b.z; acc[3][3]+=a.w*b.w;
    }
    __syncthreads();
  }
  const float4 bb=*(const float4*)(bi+q0+(tx<<2));
  #pragma unroll
  for(int i=0;i<4;i++){
    const int n=n0+(ty<<2)+i;
    float4 r4 = make_float4(acc[i][0]+bb.x, acc[i][1]+bb.y, acc[i][2]+bb.z, acc[i][3]+bb.w);
    *(float4*)(out+(size_t)n*HID+q0+(tx<<2)) = r4;
  }
}

// ---------------------------------------------------------------------------
// Persistent level-synchronous recurrence, v13 "16-wave blocks":
//  Round-12: launch_bounds(512,4) made the allocator target 8 waves/EU
//  (VGPR=64) -> pinned payload spilled to scratch -> 7.3GB HBM streaming.
//  Compiler law (3x measured): it lands just under a waves/EU tier; pins
//  beyond that become scratch. v13 gets 4 waves/SIMD a deadlock-free way:
//   - 256 blocks x 1024 threads (16 waves = 4/SIMD), launch_bounds(1024,4).
//     Grid 256 = 1 block/CU always schedulable -> no residency deadlock.
//   - Same 8 groups x 32 blocks as v8 (proven 81MB broadcast traffic;
//     L1 serves waves 2..16 of a block).
//   - Per-wave work HALVED vs v8: phase A 4 rows/wave (32 pinned u32 --
//     half of v8's fitting payload); phase C 2 rows/wave, Uh kept fp32 in
//     128KB LDS (numerics identical to v8's absmax-0.0 run).
//   - 2-deep parent-vector prefetch: next node's 4KB loads fly during
//     current node's FMA chain.
// ---------------------------------------------------------------------------
#define REC_GRID 256
#define GRPSH 4
#define GRP   (1<<GRPSH)            // 16 blocks per barrier-group
#define NGRP  (REC_GRID>>GRPSH)     // 16 groups

__device__ __forceinline__ void gbar(u32* bar){
  __syncthreads();
  if(threadIdx.x==0){
    __threadfence();
    u32* gen  = bar;
    u32* gcnt = bar + 16 + ((blockIdx.x>>GRPSH)<<4);
    u32* root = bar + 16 + (NGRP<<4);
    u32 g = __hip_atomic_load(gen, __ATOMIC_RELAXED, __HIP_MEMORY_SCOPE_AGENT);
    u32 a = __hip_atomic_fetch_add(gcnt, 1u, __ATOMIC_ACQ_REL, __HIP_MEMORY_SCOPE_AGENT);
    if(a == GRP-1u){
      __hip_atomic_store(gcnt, 0u, __ATOMIC_RELAXED, __HIP_MEMORY_SCOPE_AGENT);
      u32 b = __hip_atomic_fetch_add(root, 1u, __ATOMIC_ACQ_REL, __HIP_MEMORY_SCOPE_AGENT);
      if(b == NGRP-1u){
        __hip_atomic_store(root, 0u, __ATOMIC_RELAXED, __HIP_MEMORY_SCOPE_AGENT);
        __hip_atomic_fetch_add(gen, 1u, __ATOMIC_RELEASE, __HIP_MEMORY_SCOPE_AGENT);
      }
    }
    while(__hip_atomic_load(gen, __ATOMIC_ACQUIRE, __HIP_MEMORY_SCOPE_AGENT)==g){
      __builtin_amdgcn_s_sleep(8);
    }
    __threadfence();
  }
  __syncthreads();
}

// group-local barrier: the 32 blocks of node-group xg.
__device__ __forceinline__ void gbar_grp(u32* bar, int xg){
  __syncthreads();
  if(threadIdx.x==0){
    __threadfence();
    u32* gcnt = bar + 512 + (xg<<4);
    u32* ggen = bar + 512 + (xg<<4) + 8;
    u32 g = __hip_atomic_load(ggen, __ATOMIC_RELAXED, __HIP_MEMORY_SCOPE_AGENT);
    u32 a = __hip_atomic_fetch_add(gcnt, 1u, __ATOMIC_ACQ_REL, __HIP_MEMORY_SCOPE_AGENT);
    if(a == 31u){
      __hip_atomic_store(gcnt, 0u, __ATOMIC_RELAXED, __HIP_MEMORY_SCOPE_AGENT);
      __hip_atomic_fetch_add(ggen, 1u, __ATOMIC_RELEASE, __HIP_MEMORY_SCOPE_AGENT);
    }else{
      while(__hip_atomic_load(ggen, __ATOMIC_ACQUIRE, __HIP_MEMORY_SCOPE_AGENT)==g){
        __builtin_amdgcn_s_sleep(4);
      }
    }
    __threadfence();
  }
  __syncthreads();
}

// combine two accumulator slots a,b across lane stride s.
__device__ __forceinline__ float comb(float a, float b, int s, int lane){
  const bool hi = (lane & s) != 0;
  float send = hi ? a : b;
  float sel  = hi ? b : a;
  return sel + __shfl_xor(send, s, 64);
}

__device__ __forceinline__ u32 packbf(float lo, float hi){
  u32 x=__float_as_uint(lo), y=__float_as_uint(hi);
  x = (x + 0x7fffu + ((x>>16)&1u)) >> 16;
  y = (y + 0x7fffu + ((y>>16)&1u)) & 0xffff0000u;
  return y | x;
}
__device__ __forceinline__ float bf_lo(u32 u){ return __uint_as_float(u<<16); }
__device__ __forceinline__ float bf_hi(u32 u){ return __uint_as_float(u & 0xffff0000u); }

#define PIN1(v) asm volatile("" : "+v"(v))

__global__ __launch_bounds__(1024,4) void k_rec(
    const int* __restrict__ parent,
    const float* __restrict__ Uz, const float* __restrict__ Ur, const float* __restrict__ Uh,
    float* __restrict__ wz, float* __restrict__ wr, float* __restrict__ wh,
    float* __restrict__ node_h,
    const int* __restrict__ meta, const int* __restrict__ lstart, const int* __restrict__ order,
    u32* __restrict__ bar){
  __shared__ float UhL[32*HID];      // 128 KB: this block's 32 rows of U_h (fp32)
  const int t=threadIdx.x, lane=t&63, wv=t>>6;   // 16 waves
  const int xg = blockIdx.x & 7;     // node-group (32 blocks)
  const int i  = blockIdx.x >> 3;    // 0..31 within group
  const bool isZ = wv < 8;           // waves 0-7: z-rows; 8-15: r-rows
  const int rA  = (i<<5) + ((wv&7)<<2);   // phase A: 4 rows per wave
  const int rC0 = i<<5;                   // phase C: block's 32 rows
  const int nlev = meta[0];
  const int l4 = lane<<2;

  // ---- one-time staging ----
  // 4 rows of Uz (waves 0-7) or Ur (waves 8-15) -> bf16-packed regs (32 u32).
  const float* UA = isZ ? Uz : Ur;
  u32 uap[4][8];
  #pragma unroll
  for(int r=0;r<4;r++)
    #pragma unroll
    for(int c=0;c<4;c++){
      const float4 v = *(const float4*)(UA + (size_t)(rA+r)*HID + (c<<8) + l4);
      uap[r][c*2]   = packbf(v.x, v.y);
      uap[r][c*2+1] = packbf(v.z, v.w);
      PIN1(uap[r][c*2]); PIN1(uap[r][c*2+1]);
    }
  // 32 rows of Uh -> fp32 LDS.
  for(int x=t; x<32*HID; x+=1024) UhL[x] = Uh[(size_t)rC0*HID + x];
  __syncthreads();

  for(int lev=0; lev<nlev; ++lev){
    const int s=lstart[lev];
    const int L=lstart[lev+1]-s;
    // ---- phase A: z rows (waves 0-7) and r rows (waves 8-15) ----
    {
      int jj = xg;
      int n=0, p=0; float4 bb[4];
      if(jj<L){
        n=order[s+jj]; p=parent[n];
        const float* ph = node_h + (size_t)p*HID;
        #pragma unroll
        for(int c=0;c<4;c++) bb[c] = *(const float4*)(ph + (c<<8) + l4);
      }
      while(jj<L){
        const int jn = jj+8;
        int n2=0, p2=0; float4 bb2[4];
        if(jn<L){
          n2=order[s+jn]; p2=parent[n2];
          const float* ph2 = node_h + (size_t)p2*HID;
          #pragma unroll
          for(int c=0;c<4;c++) bb2[c] = *(const float4*)(ph2 + (c<<8) + l4);
        }
        const int myrow = rA + (lane&3);
        float wv0 = isZ ? wz[(size_t)n*HID + myrow] : wr[(size_t)n*HID + myrow];
        float pv0 = isZ ? 0.f : node_h[(size_t)p*HID + myrow];
        float a0=0.f,a1=0.f,a2=0.f,a3=0.f;
        #pragma unroll
        for(int c=0;c<4;c++){
          const float4 b=bb[c];
          #define ROWFMA(acc,r) { const u32 p0=uap[r][c*2], p1=uap[r][c*2+1]; \
            acc=fmaf(bf_lo(p0),b.x,acc); acc=fmaf(bf_hi(p0),b.y,acc); \
            acc=fmaf(bf_lo(p1),b.z,acc); acc=fmaf(bf_hi(p1),b.w,acc); }
          ROWFMA(a0,0) ROWFMA(a1,1) ROWFMA(a2,2) ROWFMA(a3,3)
          #undef ROWFMA
        }
        float c0=comb(a0,a1,1,lane), c1=comb(a2,a3,1,lane);
        float v=comb(c0,c1,2,lane);
        v+=__shfl_xor(v,4,64); v+=__shfl_xor(v,8,64);
        v+=__shfl_xor(v,16,64); v+=__shfl_xor(v,32,64);
        if(lane<4){
          const size_t idx=(size_t)n*HID+myrow;
          if(isZ) wz[idx]=sigmf(wv0+v);
          else    wr[idx]=sigmf(wv0+v)*pv0;
        }
        jj=jn; n=n2; p=p2;
        #pragma unroll
        for(int c=0;c<4;c++) bb[c]=bb2[c];
      }
    }
    gbar_grp(bar, xg);   // this group produced all 1024 wz/wr rows it needs
    // ---- phase C: h-candidate + state update (2 rows/wave, fp32 Uh LDS) ----
    {
      int jj = xg;
      int n=0, p=0; float4 bb[4];
      if(jj<L){
        n=order[s+jj]; p=parent[n];
        const float* bw = wr + (size_t)n*HID;
        #pragma unroll
        for(int c=0;c<4;c++) bb[c] = *(const float4*)(bw + (c<<8) + l4);
      }
      while(jj<L){
        const int jn = jj+8;
        int n2=0, p2=0; float4 bb2[4];
        if(jn<L){
          n2=order[s+jn]; p2=parent[n2];
          const float* bw2 = wr + (size_t)n2*HID;
          #pragma unroll
          for(int c=0;c<4;c++) bb2[c] = *(const float4*)(bw2 + (c<<8) + l4);
        }
        const int myrow = rC0 + (wv<<1) + (lane&1);
        float zv0 = wz[(size_t)n*HID + myrow];
        float wh0 = wh[(size_t)n*HID + myrow];
        float pv0 = node_h[(size_t)p*HID + myrow];
        float a0=0.f,a1=0.f;
        #pragma unroll
        for(int c=0;c<4;c++){
          const float4 b=bb[c];
          const float4 u0 = *(const float4*)&UhL[((wv<<1)+0)*HID + (c<<8) + l4];
          const float4 u1 = *(const float4*)&UhL[((wv<<1)+1)*HID + (c<<8) + l4];
          a0=fmaf(u0.x,b.x,a0); a0=fmaf(u0.y,b.y,a0); a0=fmaf(u0.z,b.z,a0); a0=fmaf(u0.w,b.w,a0);
          a1=fmaf(u1.x,b.x,a1); a1=fmaf(u1.y,b.y,a1); a1=fmaf(u1.z,b.z,a1); a1=fmaf(u1.w,b.w,a1);
        }
        float v=comb(a0,a1,1,lane);
        v+=__shfl_xor(v,2,64); v+=__shfl_xor(v,4,64); v+=__shfl_xor(v,8,64);
        v+=__shfl_xor(v,16,64); v+=__shfl_xor(v,32,64);
        if(lane<2){
          const float c=tanhf(wh0+v);
          node_h[(size_t)(n+1)*HID+myrow]=zv0*pv0+(1.f-zv0)*c;
        }
        jj=jn; n=n2; p=p2;
        #pragma unroll
        for(int c=0;c<4;c++) bb[c]=bb2[c];
      }
    }
    gbar(bar);   // level boundary: parents cross groups -> global
  }
}

// ---------------------------------------------------------------------------
// Leaf max + softmax + loss. Output: FP32 pred[4], loss.
// ---------------------------------------------------------------------------
__global__ __launch_bounds__(1024) void k_final(const float* __restrict__ node_h,
                                                const int* __restrict__ leaf,
                                                const float* __restrict__ Wout,
                                                const float* __restrict__ bout,
                                                const float* __restrict__ y,
                                                float* __restrict__ out){
  __shared__ int li[NLEAVES];
  __shared__ float fs[HID];
  __shared__ float logits[NCLASS];
  const int t=threadIdx.x;
  li[t]=leaf[t];
  __syncthreads();
  float m=-INFINITY;
  for(int l=0;l<NLEAVES;l++) m = fmaxf(m, node_h[(size_t)li[l]*HID + t]);
  fs[t]=m;
  __syncthreads();
  const int wave=t>>6, lane=t&63;
  if(wave<NCLASS){
    float p=0.f;
    for(int h=lane;h<HID;h+=64) p += Wout[wave*HID+h]*fs[h];
    for(int off=32; off; off>>=1) p += __shfl_down(p, off);
    if(lane==0) logits[wave]=p+bout[wave];
  }
  __syncthreads();
  if(t==0){
    float mx = fmaxf(fmaxf(logits[0],logits[1]),fmaxf(logits[2],logits[3]));
    float ev[NCLASS]; float es=0.f;
    #pragma unroll
    for(int c=0;c<NCLASS;c++){ ev[c]=expf(logits[c]-mx); es+=ev[c]; }
    float loss=0.f;
    #pragma unroll
    for(int c=0;c<NCLASS;c++){
      float p=ev[c]/es;
      out[c]=p;
      float d=y[c]-p; loss+=d*d;
    }
    out[NCLASS]=loss;
  }
}

// ---------------------------------------------------------------------------
extern "C" void kernel_launch(void* const* d_in, const int* in_sizes, int n_in,
                              void* d_out, int out_size, void* d_ws, size_t ws_size,
                              hipStream_t stream){
  (void)in_sizes; (void)n_in; (void)out_size;
  const float* x_word=(const float*)d_in[0];
  const int*   x_index=(const int*)d_in[1];
  const int*   parent =(const int*)d_in[2];
  const int*   leaf   =(const int*)d_in[3];
  const float* y      =(const float*)d_in[4];
  const float* E      =(const float*)d_in[5];
  const float* W_z=(const float*)d_in[6];  const float* U_z=(const float*)d_in[7];  const float* b_z=(const float*)d_in[8];
  const float* W_r=(const float*)d_in[9];  const float* U_r=(const float*)d_in[10]; const float* b_r=(const float*)d_in[11];
  const float* W_h=(const float*)d_in[12]; const float* U_h=(const float*)d_in[13]; const float* b_h=(const float*)d_in[14];
  const float* W_out=(const float*)d_in[15]; const float* b_out=(const float*)d_in[16];

  size_t off=0;
  char* wsb=(char*)d_ws;
  auto alloc=[&](size_t b)->void*{ void* p=wsb+off; off=(off+b+255)&~(size_t)255; return p; };
  u32*  bar    = (u32*)  alloc(4096);
  int*  meta   = (int*)  alloc(256);
  int*  lstart = (int*)  alloc((N_NODES+1)*sizeof(int));
  int*  order  = (int*)  alloc(N_NODES*sizeof(int));
  float* node_h= (float*)alloc((size_t)(N_NODES+1)*HID*sizeof(float));
  float* xe    = (float*)alloc((size_t)N_NODES*HID*sizeof(float));
  float* wz    = (float*)alloc((size_t)N_NODES*HID*sizeof(float));
  float* wr    = (float*)alloc((size_t)N_NODES*HID*sizeof(float));
  float* wh    = (float*)alloc((size_t)N_NODES*HID*sizeof(float));
  float* ET    = (float*)(wsb+off);
  const size_t need_ET = off + (size_t)VOCAB*HID*sizeof(float);
  const bool useET = (ws_size >= need_ET);

  hipMemsetAsync(bar, 0, 4096, stream);
  k_levels<<<1,1024,0,stream>>>(parent, meta, lstart, order, node_h);
  if(useET){
    k_transpose<<<dim3((VOCAB+31)/32, HID/32),256,0,stream>>>(E, ET);
    k_xe<<<N_NODES,256,0,stream>>>(ET, x_word, x_index, xe);
  }else{
    k_xe_noET<<<N_NODES,256,0,stream>>>(E, x_word, x_index, xe);
  }
  k_gemm_in<<<dim3(N_NODES/64, HID/64, 3),256,0,stream>>>(xe, W_z,W_r,W_h, b_z,b_r,b_h, wz,wr,wh);
  k_rec<<<REC_GRID,1024,0,stream>>>(parent, U_z,U_r,U_h, wz,wr,wh, node_h, meta, lstart, order, bar);
  k_final<<<1,1024,0,stream>>>(node_h, leaf, W_out, b_out, y, (float*)d_out);
}